// Round 11
// baseline (279.249 us; speedup 1.0000x reference)
//
#include <hip/hip_runtime.h>
#include <stdint.h>

// GroupedLinear: y[b, g*256+o] = sum_i x[b, g*256+i] * W[g,o,i] + bias[g,o]
// B=8192, G=16, GIN=GOUT=256. fp32 in/out, bf16 MFMA compute.
//
// ~285 MB HBM -> ~45-48 us floor @ ~6 TB/s (memset on this chip: 6.0 TB/s).
// History: v0 2-phase 128-tile ~3 blocks/CU = 100us; v3/v6 2-deep ILP
// pipeline (honored: 124 VGPR + 64 AGPR) = 90us. Per-block ILP is falsified:
// all pipes <15% busy, phase time 13.4Kcy vs ~1.5Kcy of issue work ->
// concurrency-starved. BW tracked resident blocks (3->2.85TB/s, 2+ILP->3.1).
// v7: max TLP. 64x64 tile, BK=64, 16KB LDS single-buffer, acc 2x2 (16 regs),
// waves_per_eu(6) -> ~6 blocks/CU (75% occ), 6 interleaved phase clocks
// per CU hide each other's barrier/HBM stalls. Simple 2-barrier loop
// (lgkm-only raw barrier), proven 8-chunk XOR swizzle (0 conflicts).

#define IN_F   4096
#define OUT_F  4096
#define GIN    256
#define GOUT   256

#define BM 64
#define BN 64
#define BK 64
#define KTOT 256

using short8  = __attribute__((ext_vector_type(8))) short;
using floatx4 = __attribute__((ext_vector_type(4))) float;

// round-to-nearest-even fp32 -> bf16 (branch-free)
__device__ __forceinline__ short f2bf_rne(float f) {
    unsigned u = __builtin_bit_cast(unsigned, f);
    unsigned r = u + 0x7FFFu + ((u >> 16) & 1u);
    return (short)(r >> 16);
}

__device__ __forceinline__ short8 pack8(floatx4 f0, floatx4 f1) {
    short8 p;
    p[0] = f2bf_rne(f0[0]); p[1] = f2bf_rne(f0[1]);
    p[2] = f2bf_rne(f0[2]); p[3] = f2bf_rne(f0[3]);
    p[4] = f2bf_rne(f1[0]); p[5] = f2bf_rne(f1[1]);
    p[6] = f2bf_rne(f1[2]); p[7] = f2bf_rne(f1[3]);
    return p;
}

// lgkm-only barrier: staging's global loads are consumed by pack8 before
// ds_write (data dep), so only ds ops need draining. sched_barrier per
// rule #18. Safe: proven correct in v3/v6.
#define SYNC_PHASE() do {                                        \
    asm volatile("s_waitcnt lgkmcnt(0)" ::: "memory");           \
    __builtin_amdgcn_sched_barrier(0);                           \
    __builtin_amdgcn_s_barrier();                                \
    __builtin_amdgcn_sched_barrier(0);                           \
} while (0)

__global__ __launch_bounds__(256) __attribute__((amdgpu_waves_per_eu(6)))
void grouped_linear_kernel(const float* __restrict__ X,
                           const float* __restrict__ W,
                           const float* __restrict__ Bias,
                           float* __restrict__ Out) {
    // bf16 LDS tiles, XOR-swizzled in 8-elem (16B) chunks: chunk q of row r
    // at q ^ (r&7). Row = 64 bf16 = 128B = 8 chunks -> conflict-free for
    // both ds_write_b128 and fragment ds_read_b128 (v0-proven, 0 conflicts).
    __shared__ __align__(16) short lsA[BM * BK];   // 8 KB
    __shared__ __align__(16) short lsB[BN * BK];   // 8 KB

    const int t    = threadIdx.x;
    const int lane = t & 63;
    const int wave = t >> 6;
    const int wm   = wave >> 1;     // wave row (0..1) -> 32 rows
    const int wn   = wave & 1;      // wave col (0..1) -> 32 cols
    const int lrow = lane & 15;
    const int quad = lane >> 4;     // 0..3

    // XCD swizzle: 8192 blocks, 8 chunks of 1024. Chunk c -> XCD c covers
    // bn in [8c, 8c+8) x all 128 bm: the 4 bn sharing an X panel (one group)
    // and the W panels for 8 columns stay in one XCD's L2. bm-minor order
    // puts X-panel sharers 128 apart -> co-resident (~6*32=192 blocks/XCD).
    const int bid = blockIdx.x;
    const int swz = (bid & 7) * 1024 + (bid >> 3);
    const int bn  = swz >> 7;           // 0..63 col-tiles of 64
    const int bm  = swz & 127;          // 0..127 row-tiles of 64
    const int g   = bn >> 2;            // group (4 col-tiles per group)
    const int row0 = bm * BM;
    const int col0 = bn * BN;
    const int nlb  = (bn & 3) * BN;     // N offset inside this group's W

    const float* Wg = W + (size_t)g * GOUT * GIN + (size_t)nlb * GIN;
    const float* Xg = X + (size_t)row0 * IN_F + g * GIN;

    floatx4 acc[2][2];
    #pragma unroll
    for (int i = 0; i < 2; ++i)
        #pragma unroll
        for (int j = 0; j < 2; ++j)
            acc[i][j] = (floatx4){0.f, 0.f, 0.f, 0.f};

    // staging geometry: 8 threads cover one 64-float row (32B/lane);
    // 256 threads = 32 rows/pass, 2 passes per 64-row tile.
    const int c8 = (t & 7) * 8;     // float offset in the 64-wide K slice
    const int q0 = (t & 7);
    const int r0 = (t >> 3);        // 0..31

    for (int kt = 0; kt < KTOT / BK; ++kt) {
        const int kbase = kt * BK;

        // ---- stage A (x) and B (W): fp32 -> bf16 LDS, swizzled ----
        #pragma unroll
        for (int it = 0; it < 2; ++it) {
            int r = r0 + 32 * it;
            const float* src = Xg + (size_t)r * IN_F + kbase + c8;
            floatx4 f0 = *(const floatx4*)src;
            floatx4 f1 = *(const floatx4*)(src + 4);
            int q = q0 ^ (r & 7);
            *(short8*)&lsA[r * BK + q * 8] = pack8(f0, f1);
        }
        #pragma unroll
        for (int it = 0; it < 2; ++it) {
            int n = r0 + 32 * it;
            const float* src = Wg + (size_t)n * GIN + kbase + c8;
            floatx4 f0 = *(const floatx4*)src;
            floatx4 f1 = *(const floatx4*)(src + 4);
            int q = q0 ^ (n & 7);
            *(short8*)&lsB[n * BK + q * 8] = pack8(f0, f1);
        }
        SYNC_PHASE();

        // ---- compute: 2 MFMA K-substeps of 32, 2x2 frags ----
        #pragma unroll
        for (int kk = 0; kk < 2; ++kk) {
            int qs = kk * 4 + quad;             // chunk index 0..7
            short8 a[2], b[2];
            #pragma unroll
            for (int i = 0; i < 2; ++i) {
                int r = wm * 32 + i * 16 + lrow;
                a[i] = *(const short8*)&lsA[r * BK + ((qs ^ (r & 7)) * 8)];
            }
            #pragma unroll
            for (int j = 0; j < 2; ++j) {
                int n = wn * 32 + j * 16 + lrow;
                b[j] = *(const short8*)&lsB[n * BK + ((qs ^ (n & 7)) * 8)];
            }
            #pragma unroll
            for (int i = 0; i < 2; ++i)
                #pragma unroll
                for (int j = 0; j < 2; ++j)
                    acc[i][j] = __builtin_amdgcn_mfma_f32_16x16x32_bf16(
                        a[i], b[j], acc[i][j], 0, 0, 0);
        }
        SYNC_PHASE();
    }

    // ---- epilogue: C/D layout col=lane&15, row=quad*4+reg; add bias ----
    #pragma unroll
    for (int j = 0; j < 2; ++j) {
        int gc = col0 + wn * 32 + j * 16 + lrow;   // global out column
        float bias = Bias[gc];
        #pragma unroll
        for (int i = 0; i < 2; ++i) {
            int gr = row0 + wm * 32 + i * 16 + quad * 4;
            floatx4 v = acc[i][j];
            #pragma unroll
            for (int rg = 0; rg < 4; ++rg)
                Out[(size_t)(gr + rg) * OUT_F + gc] = v[rg] + bias;
        }
    }
}

extern "C" void kernel_launch(void* const* d_in, const int* in_sizes, int n_in,
                              void* d_out, int out_size, void* d_ws, size_t ws_size,
                              hipStream_t stream) {
    const float* X    = (const float*)d_in[0];   // [8192, 4096]
    const float* W    = (const float*)d_in[1];   // [16, 256, 256]
    const float* Bias = (const float*)d_in[2];   // [16, 256]
    float*       Out  = (float*)d_out;           // [8192, 4096]

    dim3 grid(128 * 64);   // 128 M-tiles x 64 N-tiles of 64x64
    dim3 block(256);
    grouped_linear_kernel<<<grid, block, 0, stream>>>(X, W, Bias, Out);
}

// Round 14
// 260.625 us; speedup vs baseline: 1.0715x; 1.0715x over previous
//
#include <hip/hip_runtime.h>
#include <stdint.h>

// GroupedLinear: y[b, g*256+o] = sum_i x[b, g*256+i] * W[g,o,i] + bias[g,o]
// B=8192, G=16, GIN=GOUT=256. fp32 in/out, bf16 MFMA compute.
//
// ~260 MB compulsory HBM. History: v0 128-tile 2ph = 100us (2.85 TB/s);
// v6 ILP pipeline = 90us (3.1 TB/s, ILP falsified); v7 64-tile TLP = 119us:
// occupancy 68%, issue rate 3.4 TB/s (best), BUT FETCH 263 MB -- bm-minor
// order put X-panel sharers 128 blocks (16 MB) apart -> L2 evicted X, ~2x
// refetch. Time = 404 MB / 3.4 TB/s exactly.
// v8 = v7 with ONLY the within-XCD order changed to supertiles:
// (bmblk, bn, bm_i): 64-block supertile = 8 bm x 8 bn; X-panel sharers
// (4 bn of a group, same bm) <=24 blocks apart -> co-resident; supertile
// footprint 1.5 MB < 4 MB L2; W (512 KB/XCD) L2-resident all run.

#define IN_F   4096
#define OUT_F  4096
#define GIN    256
#define GOUT   256

#define BM 64
#define BN 64
#define BK 64
#define KTOT 256

using short8  = __attribute__((ext_vector_type(8))) short;
using floatx4 = __attribute__((ext_vector_type(4))) float;

// round-to-nearest-even fp32 -> bf16 (branch-free)
__device__ __forceinline__ short f2bf_rne(float f) {
    unsigned u = __builtin_bit_cast(unsigned, f);
    unsigned r = u + 0x7FFFu + ((u >> 16) & 1u);
    return (short)(r >> 16);
}

__device__ __forceinline__ short8 pack8(floatx4 f0, floatx4 f1) {
    short8 p;
    p[0] = f2bf_rne(f0[0]); p[1] = f2bf_rne(f0[1]);
    p[2] = f2bf_rne(f0[2]); p[3] = f2bf_rne(f0[3]);
    p[4] = f2bf_rne(f1[0]); p[5] = f2bf_rne(f1[1]);
    p[6] = f2bf_rne(f1[2]); p[7] = f2bf_rne(f1[3]);
    return p;
}

// lgkm-only barrier: staging's global loads are consumed by pack8 before
// ds_write (data dep), so only ds ops need draining. sched_barrier per
// rule #18. Proven correct v3/v6/v7.
#define SYNC_PHASE() do {                                        \
    asm volatile("s_waitcnt lgkmcnt(0)" ::: "memory");           \
    __builtin_amdgcn_sched_barrier(0);                           \
    __builtin_amdgcn_s_barrier();                                \
    __builtin_amdgcn_sched_barrier(0);                           \
} while (0)

__global__ __launch_bounds__(256) __attribute__((amdgpu_waves_per_eu(6)))
void grouped_linear_kernel(const float* __restrict__ X,
                           const float* __restrict__ W,
                           const float* __restrict__ Bias,
                           float* __restrict__ Out) {
    // bf16 LDS tiles, XOR-swizzled in 8-elem (16B) chunks: chunk q of row r
    // at q ^ (r&7) -> conflict-free ds_write_b128 / ds_read_b128 (0 measured).
    __shared__ __align__(16) short lsA[BM * BK];   // 8 KB
    __shared__ __align__(16) short lsB[BN * BK];   // 8 KB

    const int t    = threadIdx.x;
    const int lane = t & 63;
    const int wave = t >> 6;
    const int wm   = wave >> 1;     // wave row (0..1) -> 32 rows
    const int wn   = wave & 1;      // wave col (0..1) -> 32 cols
    const int lrow = lane & 15;
    const int quad = lane >> 4;     // 0..3

    // XCD supertile swizzle (v8 change). 8192 blocks; xcd = bid&7 (HW
    // round-robin) gets bn in [8*xcd, 8*xcd+8) x all 128 bm = 2 groups/XCD.
    // Within XCD: supertile = 8 bm x 8 bn (64 blocks): X-panel sharers
    // (same bm, 4 bn of one group) are <=24 blocks apart -> L2-co-resident;
    // W per XCD = 8 tiles = 512 KB, L2-resident for the whole run.
    const int bid   = blockIdx.x;
    const int xcd   = bid & 7;
    const int idx   = bid >> 3;          // 0..1023 within XCD
    const int bmblk = idx >> 6;          // 0..15  supertile row
    const int bn_l  = (idx >> 3) & 7;    // 0..7   bn within XCD
    const int bm_i  = idx & 7;           // 0..7   bm within supertile
    const int bn    = xcd * 8 + bn_l;    // 0..63 col-tiles of 64
    const int bm    = bmblk * 8 + bm_i;  // 0..127 row-tiles of 64

    const int g    = bn >> 2;            // group (4 col-tiles per group)
    const int row0 = bm * BM;
    const int col0 = bn * BN;
    const int nlb  = (bn & 3) * BN;      // N offset inside this group's W

    const float* Wg = W + (size_t)g * GOUT * GIN + (size_t)nlb * GIN;
    const float* Xg = X + (size_t)row0 * IN_F + g * GIN;

    floatx4 acc[2][2];
    #pragma unroll
    for (int i = 0; i < 2; ++i)
        #pragma unroll
        for (int j = 0; j < 2; ++j)
            acc[i][j] = (floatx4){0.f, 0.f, 0.f, 0.f};

    // staging geometry: 8 threads cover one 64-float row (32B/lane);
    // 256 threads = 32 rows/pass, 2 passes per 64-row tile.
    const int c8 = (t & 7) * 8;     // float offset in the 64-wide K slice
    const int q0 = (t & 7);
    const int r0 = (t >> 3);        // 0..31

    for (int kt = 0; kt < KTOT / BK; ++kt) {
        const int kbase = kt * BK;

        // ---- stage A (x) and B (W): fp32 -> bf16 LDS, swizzled ----
        #pragma unroll
        for (int it = 0; it < 2; ++it) {
            int r = r0 + 32 * it;
            const float* src = Xg + (size_t)r * IN_F + kbase + c8;
            floatx4 f0 = *(const floatx4*)src;
            floatx4 f1 = *(const floatx4*)(src + 4);
            int q = q0 ^ (r & 7);
            *(short8*)&lsA[r * BK + q * 8] = pack8(f0, f1);
        }
        #pragma unroll
        for (int it = 0; it < 2; ++it) {
            int n = r0 + 32 * it;
            const float* src = Wg + (size_t)n * GIN + kbase + c8;
            floatx4 f0 = *(const floatx4*)src;
            floatx4 f1 = *(const floatx4*)(src + 4);
            int q = q0 ^ (n & 7);
            *(short8*)&lsB[n * BK + q * 8] = pack8(f0, f1);
        }
        SYNC_PHASE();

        // ---- compute: 2 MFMA K-substeps of 32, 2x2 frags ----
        #pragma unroll
        for (int kk = 0; kk < 2; ++kk) {
            int qs = kk * 4 + quad;             // chunk index 0..7
            short8 a[2], b[2];
            #pragma unroll
            for (int i = 0; i < 2; ++i) {
                int r = wm * 32 + i * 16 + lrow;
                a[i] = *(const short8*)&lsA[r * BK + ((qs ^ (r & 7)) * 8)];
            }
            #pragma unroll
            for (int j = 0; j < 2; ++j) {
                int n = wn * 32 + j * 16 + lrow;
                b[j] = *(const short8*)&lsB[n * BK + ((qs ^ (n & 7)) * 8)];
            }
            #pragma unroll
            for (int i = 0; i < 2; ++i)
                #pragma unroll
                for (int j = 0; j < 2; ++j)
                    acc[i][j] = __builtin_amdgcn_mfma_f32_16x16x32_bf16(
                        a[i], b[j], acc[i][j], 0, 0, 0);
        }
        SYNC_PHASE();
    }

    // ---- epilogue: C/D layout col=lane&15, row=quad*4+reg; add bias ----
    #pragma unroll
    for (int j = 0; j < 2; ++j) {
        int gc = col0 + wn * 32 + j * 16 + lrow;   // global out column
        float bias = Bias[gc];
        #pragma unroll
        for (int i = 0; i < 2; ++i) {
            int gr = row0 + wm * 32 + i * 16 + quad * 4;
            floatx4 v = acc[i][j];
            #pragma unroll
            for (int rg = 0; rg < 4; ++rg)
                Out[(size_t)(gr + rg) * OUT_F + gc] = v[rg] + bias;
        }
    }
}

extern "C" void kernel_launch(void* const* d_in, const int* in_sizes, int n_in,
                              void* d_out, int out_size, void* d_ws, size_t ws_size,
                              hipStream_t stream) {
    const float* X    = (const float*)d_in[0];   // [8192, 4096]
    const float* W    = (const float*)d_in[1];   // [16, 256, 256]
    const float* Bias = (const float*)d_in[2];   // [16, 256]
    float*       Out  = (float*)d_out;           // [8192, 4096]

    dim3 grid(128 * 64);   // 128 M-tiles x 64 N-tiles of 64x64
    dim3 block(256);
    grouped_linear_kernel<<<grid, block, 0, stream>>>(X, W, Bias, Out);
}